// Round 7
// baseline (1705.545 us; speedup 1.0000x reference)
//
#include <hip/hip_runtime.h>
#include <hip/hip_bf16.h>
#include <hip/hip_fp16.h>

#define NN 100000
#define EE 1000000
#define GG 512
#define HH 64
#define LL 7
#define NH (NN*HH)
#define GH (GG*HH)
#define EPS_GEN 1e-7f
#define EPS_BN 1e-5f
#define SCAN_BLKS 98   // ceil(NN/1024)
#define SLOTS 64
#define CONV_BLOCKS 6250   // 16 nodes per 128-thread (2-wave) block (R3/R6 proven shape)

typedef _Float16 half8  __attribute__((ext_vector_type(8)));
typedef _Float16 half4  __attribute__((ext_vector_type(4)));
typedef _Float16 half2v __attribute__((ext_vector_type(2)));
typedef float    float4v __attribute__((ext_vector_type(4)));

__device__ __constant__ int c_atom_off[9] = {0,119,124,136,148,158,164,170,172};

// h16[n][c] = fp16( vn0[c] + sum_f atom_table[x[n][f]+off_f][c] )
__global__ void k_atom_enc(const float* __restrict__ atom_table,
                           const float* __restrict__ vn0,
                           const int* __restrict__ x,
                           _Float16* __restrict__ h16) {
    int tid = blockIdx.x * blockDim.x + threadIdx.x;
    int n = tid >> 6, c = tid & 63;
    if (n >= NN) return;
    float acc = vn0[c];
    const int* xr = x + n * 9;
    #pragma unroll
    for (int f = 0; f < 9; ++f) acc += atom_table[(xr[f] + c_atom_off[f]) * HH + c];
    h16[tid] = (_Float16)acc;
}

// merged prep: W16f = fp16 conv weights pre-permuted into MFMA B-fragment order;
// ctab16 = fp16 combined bond table (c = a0 + 5*a1 + 30*a2)
__global__ void k_prep(const float* __restrict__ W, const float* __restrict__ bond,
                       _Float16* __restrict__ W16f, _Float16* __restrict__ ctab16) {
    int i = blockIdx.x * blockDim.x + threadIdx.x;
    if (i < LL * 4096) {
        int l = i / 4096, r = i % 4096;
        int j = r & 7, lane = (r >> 3) & 63, kh = (r >> 9) & 1, t = r >> 10;
        int q = (lane >> 4) & 3, c = lane & 15;
        W16f[i] = (_Float16)W[l * 4096 + (kh * 32 + q * 8 + j) * 64 + t * 16 + c];
    } else {
        int k = i - LL * 4096;
        if (k < 60 * 64) {
            int cmb = k >> 6, lane = k & 63;
            int a0 = cmb % 5, a1 = (cmb / 5) % 6, a2 = cmb / 30;
            ctab16[k] = (_Float16)(bond[a0 * 64 + lane] + bond[(5 + a1) * 64 + lane]
                                   + bond[(11 + a2) * 64 + lane]);
        }
    }
}

// ---------------- CSR build ----------------
// R7: byte-packed histogram — 4 node-counts per 32-bit word. Quarters the atomic
// cache-line footprint (R6 measured WRITE 35MB ~ 1M x 32B atomic write-through).
// atomicAdd return byte IS the within-dst rank (deg << 255 for Poisson(10), no carry).
// rec = src(17) | combo(6)<<17 | rank(9)<<23.
__global__ void k_count2(const int* __restrict__ edge_index, const int* __restrict__ edge_attr,
                         unsigned int* __restrict__ cur, unsigned int* __restrict__ recs) {
    int e = blockIdx.x * blockDim.x + threadIdx.x;
    if (e >= EE) return;
    int src = edge_index[e];
    int dst = edge_index[EE + e];
    int combo = edge_attr[e * 3] + 5 * edge_attr[e * 3 + 1] + 30 * edge_attr[e * 3 + 2];
    int sh = (dst & 3) * 8;
    unsigned int old = atomicAdd(&cur[dst >> 2], 1u << sh);
    unsigned int rank = (old >> sh) & 255u;
    recs[e] = (unsigned int)src | ((unsigned int)combo << 17) | (rank << 23);
}

// scan over byte-packed counts: each word holds counts for nodes 4w..4w+3
__global__ void k_scan1(const unsigned int* __restrict__ cnt, int* __restrict__ rp,
                        int* __restrict__ part) {
    __shared__ int s[256];
    int t = threadIdx.x, blk = blockIdx.x;
    int wi = blk * 256 + t;                 // word index (NN/4 = 25000 words exactly)
    unsigned int pw = (wi < NN / 4) ? cnt[wi] : 0u;
    int v0 = pw & 255, v1 = (pw >> 8) & 255, v2 = (pw >> 16) & 255, v3 = (pw >> 24) & 255;
    int base = blk * 1024 + t * 4;
    int s4 = v0 + v1 + v2 + v3;
    s[t] = s4;
    __syncthreads();
    for (int off = 1; off < 256; off <<= 1) {
        int x = (t >= off) ? s[t - off] : 0;
        __syncthreads();
        s[t] += x;
        __syncthreads();
    }
    int excl = s[t] - s4;
    if (t == 255) part[blk] = s[255];
    if (base + 0 < NN) rp[base + 0] = excl;
    if (base + 1 < NN) rp[base + 1] = excl + v0;
    if (base + 2 < NN) rp[base + 2] = excl + v0 + v1;
    if (base + 3 < NN) rp[base + 3] = excl + v0 + v1 + v2;
}

__global__ void k_scan2(int* __restrict__ part) {
    __shared__ int s[128];
    int t = threadIdx.x;
    int v = (t < SCAN_BLKS) ? part[t] : 0;
    s[t] = v;
    __syncthreads();
    for (int off = 1; off < 128; off <<= 1) {
        int x = (t >= off) ? s[t - off] : 0;
        __syncthreads();
        s[t] += x;
        __syncthreads();
    }
    if (t < SCAN_BLKS) part[t] = s[t] - v;
}

__global__ void k_scan3(int* __restrict__ rp, const int* __restrict__ part) {
    int i = blockIdx.x * blockDim.x + threadIdx.x;
    if (i < NN) rp[i] += part[i >> 10];
    if (i == 0) rp[NN] = EE;
}

// atomic-free scatter: slot = rp[dst] + rank (rank from the packed record)
__global__ void k_fill2(const int* __restrict__ edge_index, const unsigned int* __restrict__ recs,
                        const int* __restrict__ rp, unsigned int* __restrict__ edges) {
    int e = blockIdx.x * blockDim.x + threadIdx.x;
    if (e >= EE) return;
    unsigned int rec = recs[e];
    int dst = edge_index[EE + e];
    edges[rp[dst] + (rec >> 23)] = rec & 0x7FFFFFu;
}

// ---------------- conv: gather/aggregate -> MFMA GEMM (+res) + stats ----------------
// R6-proven: 2 waves/block on one 16-node tile; lane-parallel coalesced edge-record
// load + __shfl distribution; ctab16 staged in LDS. FROZEN this round (control).
// NOTE (R1 lesson): NO extra per-edge gather streams (VN stays a separate pass).
// NOTE (R4/R5 lessons): no ticket dispensers; no independent-wave repackaging.
// NOTE (R12 lesson): no non-temporal hints; no device-scope fences.
__global__ __launch_bounds__(128, 8) void k_conv_mfma(
        const _Float16* __restrict__ h16, const float* res,
        const int* __restrict__ rp, const unsigned int* __restrict__ edges,
        const _Float16* __restrict__ ctab16, const _Float16* __restrict__ W16f,
        const float* __restrict__ bvec,
        float* __restrict__ out, float* __restrict__ statsPart) {
    __shared__ __align__(16) _Float16 sA[16 * 64];   // 2KB accumulator tile
    __shared__ __align__(16) _Float16 sC[60 * 64];   // 7.5KB combined bond table
    int lane = threadIdx.x & 63;
    int wv = threadIdx.x >> 6;   // wave 0/1
    int g  = lane >> 5;          // node group 0/1 within wave
    int sg = (lane >> 4) & 1;    // edge parity sub-group
    int cc = (lane & 15) * 4;    // channel base (half4)
    int q = lane >> 4;           // mfma quad
    int c = lane & 15;           // mfma col
    int lane32 = lane & 31;
    int n0 = blockIdx.x * 16;
    const half4 z4 = {(_Float16)0, (_Float16)0, (_Float16)0, (_Float16)0};

    // stage ctab16 into LDS: 7680B = 480 x int4, 128 threads
    for (int i = threadIdx.x; i < 480; i += 128)
        ((int4*)sC)[i] = ((const int4*)ctab16)[i];

    // B fragments for this wave's two column-quadrants (pre-permuted, coalesced)
    const half8* wf = (const half8*)W16f;
    half8 bf[2][2];
    #pragma unroll
    for (int t = 0; t < 2; ++t) {
        bf[t][0] = wf[((wv * 2 + t) * 2 + 0) * 64 + lane];
        bf[t][1] = wf[((wv * 2 + t) * 2 + 1) * 64 + lane];
    }
    __syncthreads();   // sC ready

    // ---- phase 1: aggregation, one node per 32-lane group, 4 nodes per group ----
    #pragma unroll 1
    for (int i = 0; i < 4; ++i) {
        int r_loc = wv * 8 + g * 4 + i;      // sA row 0..15
        int n = n0 + r_loc;
        int beg = rp[n], end = rp[n + 1];
        int deg = end - beg;
        half4 sv = *(const half4*)(h16 + (size_t)n * 64 + cc);   // self (early issue)
        float ax = 0.f, ay = 0.f, az = 0.f, aw = 0.f;
        #pragma unroll 1
        for (int base = beg; base < end; base += 32) {
            int idx = base + lane32;
            idx = idx < end ? idx : end - 1;          // clamp (unused lanes)
            unsigned int rl = edges[idx];             // ONE coalesced record load
            int m = end - base; if (m > 32) m = 32;
            int t = 0;
            for (; t + 8 <= m; t += 8) {   // 8 edges: sub-group sg takes t+2u+sg
                unsigned int r[4];
                #pragma unroll
                for (int u = 0; u < 4; ++u)
                    r[u] = __shfl(rl, (g << 5) + t + 2 * u + sg, 64);
                half4 hh[4], tt[4];
                #pragma unroll
                for (int u = 0; u < 4; ++u) {
                    hh[u] = *(const half4*)(h16 + (size_t)(r[u] & 0x1FFFF) * 64 + cc);
                    tt[u] = *(const half4*)(sC + ((r[u] >> 17) & 63) * 64 + cc);
                }
                #pragma unroll
                for (int u = 0; u < 4; ++u) {
                    half4 mm = __builtin_elementwise_max(hh[u] + tt[u], z4);  // pk ops
                    ax += (float)mm[0]; ay += (float)mm[1];
                    az += (float)mm[2]; aw += (float)mm[3];
                }
            }
            for (; t < m; t += 2) {        // masked tail: 1 edge per sub-group/iter
                int e0 = t + sg;
                bool v0 = e0 < m;
                unsigned int r0 = __shfl(rl, (g << 5) + (v0 ? e0 : 0), 64);
                half4 h0 = *(const half4*)(h16 + (size_t)(r0 & 0x1FFFF) * 64 + cc);
                half4 t0 = *(const half4*)(sC + ((r0 >> 17) & 63) * 64 + cc);
                half4 m0 = __builtin_elementwise_max(h0 + t0, z4);
                if (v0) {
                    ax += (float)m0[0]; ay += (float)m0[1];
                    az += (float)m0[2]; aw += (float)m0[3];
                }
            }
        }
        // reduce across sub-groups (lane bit 4); replicates
        ax += __shfl_xor(ax, 16, 64); ay += __shfl_xor(ay, 16, 64);
        az += __shfl_xor(az, 16, 64); aw += __shfl_xor(aw, 16, 64);
        float ed = (float)deg * EPS_GEN;
        ax += (float)sv[0] + ed; ay += (float)sv[1] + ed;
        az += (float)sv[2] + ed; aw += (float)sv[3] + ed;
        if (sg == 0) {
            half4 pk;
            pk[0] = (_Float16)ax; pk[1] = (_Float16)ay;
            pk[2] = (_Float16)az; pk[3] = (_Float16)aw;
            *(half4*)(&sA[r_loc * 64 + cc]) = pk;
        }
    }
    __syncthreads();   // cross-wave: both waves' sA rows must be visible

    // ---- phase 2: MFMA (each wave: all 16 rows x its 32 columns) ----
    half8 af0 = *(const half8*)(sA + c * 64 + q * 8);         // kh=0
    half8 af1 = *(const half8*)(sA + c * 64 + 32 + q * 8);    // kh=1
    float4v d[2];
    #pragma unroll
    for (int t = 0; t < 2; ++t) {
        d[t] = (float4v){0.f, 0.f, 0.f, 0.f};
        d[t] = __builtin_amdgcn_mfma_f32_16x16x32_f16(af0, bf[t][0], d[t], 0, 0, 0);
        d[t] = __builtin_amdgcn_mfma_f32_16x16x32_f16(af1, bf[t][1], d[t], 0, 0, 0);
    }

    // ---- epilogue: bias + residual + store + stats partials ----
    float ps[2], pq[2];
    #pragma unroll
    for (int t = 0; t < 2; ++t) { ps[t] = 0.f; pq[t] = 0.f; }
    #pragma unroll
    for (int t = 0; t < 2; ++t) {
        int tg = wv * 2 + t;
        float bz = bvec[tg * 16 + c];
        #pragma unroll
        for (int r = 0; r < 4; ++r) {
            int row = n0 + q * 4 + r;
            float val = d[t][r] + bz;
            size_t off = (size_t)row * 64 + tg * 16 + c;
            if (res) val += res[off];
            out[off] = val;
            ps[t] += val;
            pq[t] = fmaf(val, val, pq[t]);
        }
    }
    #pragma unroll
    for (int t = 0; t < 2; ++t) {
        ps[t] += __shfl_xor(ps[t], 16, 64); ps[t] += __shfl_xor(ps[t], 32, 64);
        pq[t] += __shfl_xor(pq[t], 16, 64); pq[t] += __shfl_xor(pq[t], 32, 64);
    }
    float* sp = statsPart + ((blockIdx.x * 2 + wv) & (SLOTS - 1)) * 128;
    if (lane < 16) {
        #pragma unroll
        for (int t = 0; t < 2; ++t) {
            int tg = wv * 2 + t;
            atomicAdd(&sp[tg * 16 + lane], ps[t]);
            atomicAdd(&sp[64 + tg * 16 + lane], pq[t]);
        }
    }
}

// ---------------- BN / pooling ----------------

// h16 = fp16(relu(bn(h))); vt[batch[n]] += run-length aggregated; chunk=8 nodes/wave.
// Stats fold done per-block with ALL 256 threads (strided, coalesced lines).
__global__ void k_bn_relu_vt2(const float* __restrict__ h, const float* __restrict__ spart,
                              const float* __restrict__ gamma, const float* __restrict__ beta,
                              const int* __restrict__ batch,
                              _Float16* __restrict__ h16, float* __restrict__ vt) {
    __shared__ float sTmp[256];
    __shared__ float sMS[128];
    {
        int ch = threadIdx.x & 127, hf = threadIdx.x >> 7;
        float a = 0.f;
        #pragma unroll 8
        for (int i = hf; i < SLOTS; i += 2) a += spart[i * 128 + ch];
        sTmp[threadIdx.x] = a;
    }
    __syncthreads();
    if (threadIdx.x < 64) {
        int c = threadIdx.x;
        float s = sTmp[c] + sTmp[128 + c];
        float q = sTmp[64 + c] + sTmp[192 + c];
        float mu = s * (1.f / NN);
        float var = q * (1.f / NN) - mu * mu;
        sMS[c] = mu;
        sMS[64 + c] = rsqrtf(var + EPS_BN);
    }
    __syncthreads();
    int lane = threadIdx.x & 63;
    int w = blockIdx.x * 4 + (threadIdx.x >> 6);
    int n0 = w * 8;
    if (n0 >= NN) return;
    int n1 = min(n0 + 8, NN);
    float mu = sMS[lane];
    float inv = sMS[64 + lane] * gamma[lane];
    float bet = beta[lane];
    float acc = 0.f;
    int gcur = batch[n0];
    for (int n = n0; n < n1; ++n) {
        float v = fmaxf((h[(size_t)n * 64 + lane] - mu) * inv + bet, 0.f);
        h16[(size_t)n * 64 + lane] = (_Float16)v;
        int g = batch[n];
        if (g != gcur) {
            atomicAdd(&vt[(size_t)gcur * 64 + lane], acc);
            acc = 0.f; gcur = g;
        }
        acc += v;
    }
    atomicAdd(&vt[(size_t)gcur * 64 + lane], acc);
}

// R7: fused virtual-node MLP — replaces the two k_vn_gemm dispatches. ONE block,
// 512 threads (8 waves x 64 rows). The t1-BN-stats global dependency that forced
// two dispatches becomes an in-block LDS reduction. t1 staged via the L2-hot t1g
// buffer (rule #20: no runtime-indexed register arrays). For l>=2, addmat==t2
// (same buffer) is safe: each wave writes only rows it already read, in order.
// t2stats written as plain stores (raw sums; same format consumers expect).
__global__ __launch_bounds__(512, 1) void k_vn_mlp(
        float* __restrict__ in,
        const float* addmat, const float* add_stats,
        const float* add_g, const float* add_be,
        const float* addvec,
        const float* __restrict__ W1, const float* __restrict__ b1,
        const float* __restrict__ g1, const float* __restrict__ be1,
        const float* __restrict__ W2, const float* __restrict__ b2,
        float* __restrict__ t1g, float* t2,
        float* __restrict__ t2stats) {
    __shared__ float sW1[4096];
    __shared__ float sW2[4096];
    __shared__ float sRed[2][8][64];
    for (int i = threadIdx.x; i < 4096; i += 512) { sW1[i] = W1[i]; sW2[i] = W2[i]; }
    int lane = threadIdx.x & 63, wv = threadIdx.x >> 6;   // 8 waves, 64 rows each
    float amu = 0.f, ainv = 0.f, abe = 0.f;
    if (addmat) {
        float mu = add_stats[lane] * (1.f / GG);
        float var = add_stats[64 + lane] * (1.f / GG) - mu * mu;
        amu = mu; ainv = rsqrtf(var + EPS_BN) * add_g[lane]; abe = add_be[lane];
    }
    float av = addvec ? addvec[lane] : 0.f;
    float b1l = b1[lane], g1l = g1[lane], be1l = be1[lane], b2l = b2[lane];
    __syncthreads();   // sW ready
    int r0 = wv * 64;
    float ps = 0.f, pq = 0.f;
    #pragma unroll 1
    for (int r = r0; r < r0 + 64; ++r) {
        float va = in[r * 64 + lane];
        in[r * 64 + lane] = 0.f;                       // clear vt for next layer
        if (addmat) va += fmaxf((addmat[r * 64 + lane] - amu) * ainv + abe, 0.f);
        va += av;
        float a0 = b1l, a1 = 0.f;                      // split acc chain
        #pragma unroll
        for (int k = 0; k < 64; k += 2) {
            a0 = fmaf(__shfl(va, k, 64), sW1[k * 64 + lane], a0);
            a1 = fmaf(__shfl(va, k + 1, 64), sW1[(k + 1) * 64 + lane], a1);
        }
        float acc = a0 + a1;
        t1g[r * 64 + lane] = acc;
        ps += acc; pq = fmaf(acc, acc, pq);
    }
    sRed[0][wv][lane] = ps;
    sRed[1][wv][lane] = pq;
    __syncthreads();   // also drains t1g stores (barrier implies vmcnt(0))
    float s = 0.f, q = 0.f;
    #pragma unroll
    for (int i = 0; i < 8; ++i) { s += sRed[0][i][lane]; q += sRed[1][i][lane]; }
    float mu1 = s * (1.f / GG);
    float var1 = q * (1.f / GG) - mu1 * mu1;
    float inv1 = rsqrtf(var1 + EPS_BN) * g1l;
    float ps2 = 0.f, pq2 = 0.f;
    #pragma unroll 1
    for (int r = r0; r < r0 + 64; ++r) {
        float va = fmaxf((t1g[r * 64 + lane] - mu1) * inv1 + be1l, 0.f);
        float a0 = b2l, a1 = 0.f;
        #pragma unroll
        for (int k = 0; k < 64; k += 2) {
            a0 = fmaf(__shfl(va, k, 64), sW2[k * 64 + lane], a0);
            a1 = fmaf(__shfl(va, k + 1, 64), sW2[(k + 1) * 64 + lane], a1);
        }
        float acc = a0 + a1;
        t2[r * 64 + lane] = acc;
        ps2 += acc; pq2 = fmaf(acc, acc, pq2);
    }
    __syncthreads();   // sRed reuse
    sRed[0][wv][lane] = ps2;
    sRed[1][wv][lane] = pq2;
    __syncthreads();
    if (threadIdx.x < 64) {
        float s2 = 0.f, q2 = 0.f;
        #pragma unroll
        for (int i = 0; i < 8; ++i) {
            s2 += sRed[0][i][threadIdx.x];
            q2 += sRed[1][i][threadIdx.x];
        }
        t2stats[threadIdx.x] = s2;
        t2stats[64 + threadIdx.x] = q2;
    }
}

// h16[n] += bnrelu(t2)[batch[n]]  (16 threads/node, half4/float4 wide)
__global__ void k_addvn16(_Float16* __restrict__ h16, const float* __restrict__ t2,
                          const float* __restrict__ stats,
                          const float* __restrict__ g2, const float* __restrict__ be2,
                          const int* __restrict__ batch) {
    int tid = blockIdx.x * blockDim.x + threadIdx.x;
    int n = tid >> 4, p = tid & 15;
    if (n >= NN) return;
    int c0 = p * 4;
    float mu[4], iv[4], be[4];
    #pragma unroll
    for (int k = 0; k < 4; ++k) {
        int ci = c0 + k;
        float m = stats[ci] * (1.f / GG);
        float v = stats[64 + ci] * (1.f / GG) - m * m;
        mu[k] = m;
        iv[k] = rsqrtf(v + EPS_BN) * g2[ci];
        be[k] = be2[ci];
    }
    int g = batch[n];
    float4 t = *(const float4*)(t2 + (size_t)g * 64 + c0);
    float tv[4] = {t.x, t.y, t.z, t.w};
    half4 hv = *(half4*)(h16 + (size_t)n * 64 + c0);
    half4 o;
    #pragma unroll
    for (int k = 0; k < 4; ++k) {
        float a = fmaxf((tv[k] - mu[k]) * iv[k] + be[k], 0.f);
        o[k] = (_Float16)((float)hv[k] + a);
    }
    *(half4*)(h16 + (size_t)n * 64 + c0) = o;
}

// final BN + mean-pool, run-length aggregated; chunk=16; stats fold inlined
__global__ void k_pool2(const float* __restrict__ h, const float* __restrict__ spart,
                        const float* __restrict__ gamma, const float* __restrict__ beta,
                        const int* __restrict__ batch,
                        float* __restrict__ out, float* __restrict__ cnt) {
    __shared__ float sTmp[256];
    __shared__ float sMS[128];
    {
        int ch = threadIdx.x & 127, hf = threadIdx.x >> 7;
        float a = 0.f;
        #pragma unroll 8
        for (int i = hf; i < SLOTS; i += 2) a += spart[i * 128 + ch];
        sTmp[threadIdx.x] = a;
    }
    __syncthreads();
    if (threadIdx.x < 64) {
        int c = threadIdx.x;
        float s = sTmp[c] + sTmp[128 + c];
        float q = sTmp[64 + c] + sTmp[192 + c];
        float mu = s * (1.f / NN);
        float var = q * (1.f / NN) - mu * mu;
        sMS[c] = mu;
        sMS[64 + c] = rsqrtf(var + EPS_BN);
    }
    __syncthreads();
    int lane = threadIdx.x & 63;
    int w = blockIdx.x * 4 + (threadIdx.x >> 6);
    int n0 = w * 16;
    if (n0 >= NN) return;
    int n1 = min(n0 + 16, NN);
    float mu = sMS[lane];
    float inv = sMS[64 + lane] * gamma[lane];
    float bet = beta[lane];
    float acc = 0.f;
    int run = 0;
    int gcur = batch[n0];
    for (int n = n0; n < n1; ++n) {
        float v = (h[(size_t)n * 64 + lane] - mu) * inv + bet;
        int g = batch[n];
        if (g != gcur) {
            atomicAdd(&out[(size_t)gcur * 64 + lane], acc);
            if (lane == 0) atomicAdd(&cnt[gcur], (float)run);
            acc = 0.f; run = 0; gcur = g;
        }
        acc += v; run++;
    }
    atomicAdd(&out[(size_t)gcur * 64 + lane], acc);
    if (lane == 0) atomicAdd(&cnt[gcur], (float)run);
}

__global__ void k_div(float* __restrict__ out, const float* __restrict__ cnt) {
    int tid = blockIdx.x * blockDim.x + threadIdx.x;
    if (tid >= GH) return;
    out[tid] /= fmaxf(cnt[tid >> 6], 1.0f);
}

extern "C" void kernel_launch(void* const* d_in, const int* in_sizes, int n_in,
                              void* d_out, int out_size, void* d_ws, size_t ws_size,
                              hipStream_t stream) {
    const float* atom_table = (const float*)d_in[0];
    const float* bond_table = (const float*)d_in[1];
    const float* vn0   = (const float*)d_in[2];
    const float* gcn_W = (const float*)d_in[3];
    const float* gcn_b = (const float*)d_in[4];
    const float* ng    = (const float*)d_in[5];
    const float* nb    = (const float*)d_in[6];
    const float* vn_W1 = (const float*)d_in[7];
    const float* vn_b1 = (const float*)d_in[8];
    const float* vn_g1 = (const float*)d_in[9];
    const float* vn_be1= (const float*)d_in[10];
    const float* vn_W2 = (const float*)d_in[11];
    const float* vn_b2 = (const float*)d_in[12];
    const float* vn_g2 = (const float*)d_in[13];
    const float* vn_be2= (const float*)d_in[14];
    const int* x          = (const int*)d_in[15];
    const int* edge_index = (const int*)d_in[16];
    const int* edge_attr  = (const int*)d_in[17];
    const int* batch      = (const int*)d_in[18];

    float* ws = (float*)d_ws;
    float* hB   = ws;                                 // NH fp32 (running h)
    _Float16* h16 = (_Float16*)(ws + (size_t)NH);     // NH fp16 (gather source)
    float* vt   = ws + (size_t)NH + NH / 2;           // GH
    float* t1   = vt + GH;                            // GH (vn-MLP staging)
    float* t2   = t1 + GH;                            // GH
    float* convStatsP = t2 + GH;                      // 7 * SLOTS * 128
    float* msAll      = convStatsP + 7 * SLOTS * 128; // 7 * 128 (layout keep)
    float* vn1Stats   = msAll + 7 * 128;              // 6*128 (unused, layout keep)
    float* vn2Stats   = vn1Stats + 6 * 128;           // 6*128
    float* cnt    = vn2Stats + 6 * 128;               // GG
    _Float16* ctab16 = (_Float16*)(cnt + GG);         // 60*64 fp16
    _Float16* W16f   = ctab16 + 60 * 64;              // 7*4096 fp16 (fragment order)
    int*   rp     = (int*)(W16f + LL * 4096);         // NN+1 (+1 pad -> even offsets)
    int*   cur    = rp + (NN + 2);                    // NN/4 words (byte-packed counts)
    int*   part   = cur + NN;                         // 128
    unsigned int* edges = (unsigned int*)(part + 128);  // EE
    // recs is CSR-build scratch only; alias the h16 region (atom_enc runs after fill2)
    unsigned int* recs = (unsigned int*)h16;            // EE (4MB <= 12.8MB h16)

    const int blkN = NH / 256;               // 25000
    const int blkG = (GH + 255) / 256;       // 128
    const int blkE = (EE + 255) / 256;       // 3907
    const int blkRL = ((NN + 7) / 8 + 3) / 4;   // 3125
    const int blkPL = ((NN + 15) / 16 + 3) / 4; // 1563
    const int blkAV = (NN * 16) / 256;       // 6250
    const int blkPR = (LL * 4096 + 60 * 64 + 255) / 256;  // 127
    float* outp = (float*)d_out;

    // ---- CSR build first (recs aliases h16; must finish before k_atom_enc) ----
    hipMemsetAsync(cur, 0, (size_t)(NN / 4) * 4, stream);    // 100KB byte-packed
    k_count2<<<blkE, 256, 0, stream>>>(edge_index, edge_attr, (unsigned int*)cur, recs);
    k_scan1<<<SCAN_BLKS, 256, 0, stream>>>((const unsigned int*)cur, rp, part);
    k_scan2<<<1, 128, 0, stream>>>(part);
    k_scan3<<<(NN + 255) / 256, 256, 0, stream>>>(rp, part);
    k_fill2<<<blkE, 256, 0, stream>>>(edge_index, recs, rp, edges);

    k_atom_enc<<<blkN, 256, 0, stream>>>(atom_table, vn0, x, h16);
    k_prep<<<blkPR, 256, 0, stream>>>(gcn_W, bond_table, W16f, ctab16);
    hipMemsetAsync(convStatsP, 0, (7 * SLOTS * 128 + 7 * 128 + 12 * 128) * 4, stream);
    hipMemsetAsync(vt, 0, (size_t)GH * 4, stream);

    // ---- layer 0: hB = (h16 + agg(h16)) @ W0 + b0 ----
    k_conv_mfma<<<CONV_BLOCKS, 128, 0, stream>>>(h16, nullptr, rp, edges, ctab16, W16f,
                                                 gcn_b, hB, convStatsP);

    for (int l = 1; l < LL; ++l) {
        // h16 = relu(bn(hB)) (stats folded in-block); vt = segment_sum(h16)
        k_bn_relu_vt2<<<blkRL, 256, 0, stream>>>(hB, convStatsP + (size_t)(l - 1) * SLOTS * 128,
                                                 ng + (size_t)(l - 1) * HH,
                                                 nb + (size_t)(l - 1) * HH, batch, h16, vt);
        // fused vn-MLP: t2 = bnrelu( (vt + vn_prev) @ W1 + b1 ) @ W2 + b2, + t2 stats
        if (l == 1)
            k_vn_mlp<<<1, 512, 0, stream>>>(vt, nullptr, nullptr, nullptr, nullptr, vn0,
                                            vn_W1, vn_b1, vn_g1, vn_be1,
                                            vn_W2, vn_b2, t1, t2, vn2Stats);
        else
            k_vn_mlp<<<1, 512, 0, stream>>>(vt, t2, vn2Stats + (size_t)(l - 2) * 128,
                                            vn_g2 + (size_t)(l - 2) * HH,
                                            vn_be2 + (size_t)(l - 2) * HH, nullptr,
                                            vn_W1 + (size_t)(l - 1) * 4096,
                                            vn_b1 + (size_t)(l - 1) * HH,
                                            vn_g1 + (size_t)(l - 1) * HH,
                                            vn_be1 + (size_t)(l - 1) * HH,
                                            vn_W2 + (size_t)(l - 1) * 4096,
                                            vn_b2 + (size_t)(l - 1) * HH,
                                            t1, t2, vn2Stats + (size_t)(l - 1) * 128);
        // h16 += bnrelu(t2)[batch]
        k_addvn16<<<blkAV, 256, 0, stream>>>(h16, t2, vn2Stats + (size_t)(l - 1) * 128,
                                             vn_g2 + (size_t)(l - 1) * HH,
                                             vn_be2 + (size_t)(l - 1) * HH, batch);

        k_conv_mfma<<<CONV_BLOCKS, 128, 0, stream>>>(h16, hB, rp, edges, ctab16,
                                                     W16f + (size_t)l * 4096,
                                                     gcn_b + (size_t)l * HH, hB,
                                                     convStatsP + (size_t)l * SLOTS * 128);
    }

    // ---- final BN + mean pool (stats fold inlined in k_pool2) ----
    hipMemsetAsync(outp, 0, (size_t)GH * 4, stream);
    hipMemsetAsync(cnt, 0, (size_t)GG * 4, stream);
    k_pool2<<<blkPL, 256, 0, stream>>>(hB, convStatsP + (size_t)6 * SLOTS * 128,
                                       ng + (size_t)6 * HH, nb + (size_t)6 * HH,
                                       batch, outp, cnt);
    k_div<<<blkG, 256, 0, stream>>>(outp, cnt);
}

// Round 8
// 788.531 us; speedup vs baseline: 2.1629x; 2.1629x over previous
//
#include <hip/hip_runtime.h>
#include <hip/hip_bf16.h>
#include <hip/hip_fp16.h>

#define NN 100000
#define EE 1000000
#define GG 512
#define HH 64
#define LL 7
#define NH (NN*HH)
#define GH (GG*HH)
#define EPS_GEN 1e-7f
#define EPS_BN 1e-5f
#define SCAN_BLKS 98   // ceil(NN/1024)
#define SLOTS 64
#define CONV_BLOCKS 6250   // 16 nodes per 128-thread (2-wave) block (R3/R6 proven shape)

typedef _Float16 half8  __attribute__((ext_vector_type(8)));
typedef _Float16 half4  __attribute__((ext_vector_type(4)));
typedef _Float16 half2v __attribute__((ext_vector_type(2)));
typedef float    float4v __attribute__((ext_vector_type(4)));

__device__ __constant__ int c_atom_off[9] = {0,119,124,136,148,158,164,170,172};

// h16[n][c] = fp16( vn0[c] + sum_f atom_table[x[n][f]+off_f][c] )
__global__ void k_atom_enc(const float* __restrict__ atom_table,
                           const float* __restrict__ vn0,
                           const int* __restrict__ x,
                           _Float16* __restrict__ h16) {
    int tid = blockIdx.x * blockDim.x + threadIdx.x;
    int n = tid >> 6, c = tid & 63;
    if (n >= NN) return;
    float acc = vn0[c];
    const int* xr = x + n * 9;
    #pragma unroll
    for (int f = 0; f < 9; ++f) acc += atom_table[(xr[f] + c_atom_off[f]) * HH + c];
    h16[tid] = (_Float16)acc;
}

// merged prep: W16f = fp16 conv weights pre-permuted into MFMA B-fragment order;
// ctab16 = fp16 combined bond table (c = a0 + 5*a1 + 30*a2)
__global__ void k_prep(const float* __restrict__ W, const float* __restrict__ bond,
                       _Float16* __restrict__ W16f, _Float16* __restrict__ ctab16) {
    int i = blockIdx.x * blockDim.x + threadIdx.x;
    if (i < LL * 4096) {
        int l = i / 4096, r = i % 4096;
        int j = r & 7, lane = (r >> 3) & 63, kh = (r >> 9) & 1, t = r >> 10;
        int q = (lane >> 4) & 3, c = lane & 15;
        W16f[i] = (_Float16)W[l * 4096 + (kh * 32 + q * 8 + j) * 64 + t * 16 + c];
    } else {
        int k = i - LL * 4096;
        if (k < 60 * 64) {
            int cmb = k >> 6, lane = k & 63;
            int a0 = cmb % 5, a1 = (cmb / 5) % 6, a2 = cmb / 30;
            ctab16[k] = (_Float16)(bond[a0 * 64 + lane] + bond[(5 + a1) * 64 + lane]
                                   + bond[(11 + a2) * 64 + lane]);
        }
    }
}

// ---------------- CSR build ----------------
// Byte-packed histogram (R7): 4 node-counts per 32-bit word — quarters the atomic
// line footprint. atomicAdd return byte IS the within-dst rank (deg << 255).
// rec = src(17) | combo(6)<<17 | rank(9)<<23.
__global__ void k_count2(const int* __restrict__ edge_index, const int* __restrict__ edge_attr,
                         unsigned int* __restrict__ cur, unsigned int* __restrict__ recs) {
    int e = blockIdx.x * blockDim.x + threadIdx.x;
    if (e >= EE) return;
    int src = edge_index[e];
    int dst = edge_index[EE + e];
    int combo = edge_attr[e * 3] + 5 * edge_attr[e * 3 + 1] + 30 * edge_attr[e * 3 + 2];
    int sh = (dst & 3) * 8;
    unsigned int old = atomicAdd(&cur[dst >> 2], 1u << sh);
    unsigned int rank = (old >> sh) & 255u;
    recs[e] = (unsigned int)src | ((unsigned int)combo << 17) | (rank << 23);
}

// scan over byte-packed counts: each word holds counts for nodes 4w..4w+3
__global__ void k_scan1(const unsigned int* __restrict__ cnt, int* __restrict__ rp,
                        int* __restrict__ part) {
    __shared__ int s[256];
    int t = threadIdx.x, blk = blockIdx.x;
    int wi = blk * 256 + t;                 // word index (NN/4 = 25000 words exactly)
    unsigned int pw = (wi < NN / 4) ? cnt[wi] : 0u;
    int v0 = pw & 255, v1 = (pw >> 8) & 255, v2 = (pw >> 16) & 255, v3 = (pw >> 24) & 255;
    int base = blk * 1024 + t * 4;
    int s4 = v0 + v1 + v2 + v3;
    s[t] = s4;
    __syncthreads();
    for (int off = 1; off < 256; off <<= 1) {
        int x = (t >= off) ? s[t - off] : 0;
        __syncthreads();
        s[t] += x;
        __syncthreads();
    }
    int excl = s[t] - s4;
    if (t == 255) part[blk] = s[255];
    if (base + 0 < NN) rp[base + 0] = excl;
    if (base + 1 < NN) rp[base + 1] = excl + v0;
    if (base + 2 < NN) rp[base + 2] = excl + v0 + v1;
    if (base + 3 < NN) rp[base + 3] = excl + v0 + v1 + v2;
}

__global__ void k_scan2(int* __restrict__ part) {
    __shared__ int s[128];
    int t = threadIdx.x;
    int v = (t < SCAN_BLKS) ? part[t] : 0;
    s[t] = v;
    __syncthreads();
    for (int off = 1; off < 128; off <<= 1) {
        int x = (t >= off) ? s[t - off] : 0;
        __syncthreads();
        s[t] += x;
        __syncthreads();
    }
    if (t < SCAN_BLKS) part[t] = s[t] - v;
}

__global__ void k_scan3(int* __restrict__ rp, const int* __restrict__ part) {
    int i = blockIdx.x * blockDim.x + threadIdx.x;
    if (i < NN) rp[i] += part[i >> 10];
    if (i == 0) rp[NN] = EE;
}

// atomic-free scatter: slot = rp[dst] + rank (rank from the packed record)
__global__ void k_fill2(const int* __restrict__ edge_index, const unsigned int* __restrict__ recs,
                        const int* __restrict__ rp, unsigned int* __restrict__ edges) {
    int e = blockIdx.x * blockDim.x + threadIdx.x;
    if (e >= EE) return;
    unsigned int rec = recs[e];
    int dst = edge_index[EE + e];
    edges[rp[dst] + (rec >> 23)] = rec & 0x7FFFFFu;
}

// ---------------- conv: gather/aggregate -> MFMA GEMM (+res) + stats ----------------
// R6-proven: 2 waves/block on one 16-node tile; lane-parallel coalesced edge-record
// load + __shfl distribution; ctab16 staged in LDS. FROZEN (control).
// NOTE (R1 lesson): NO extra per-edge gather streams (VN stays a separate pass).
// NOTE (R4/R5 lessons): no ticket dispensers; no independent-wave repackaging.
// NOTE (R7 lesson): never shrink a grid to 1 block to save a launch.
// NOTE (R12 lesson): no non-temporal hints; no device-scope fences.
__global__ __launch_bounds__(128, 8) void k_conv_mfma(
        const _Float16* __restrict__ h16, const float* res,
        const int* __restrict__ rp, const unsigned int* __restrict__ edges,
        const _Float16* __restrict__ ctab16, const _Float16* __restrict__ W16f,
        const float* __restrict__ bvec,
        float* __restrict__ out, float* __restrict__ statsPart) {
    __shared__ __align__(16) _Float16 sA[16 * 64];   // 2KB accumulator tile
    __shared__ __align__(16) _Float16 sC[60 * 64];   // 7.5KB combined bond table
    int lane = threadIdx.x & 63;
    int wv = threadIdx.x >> 6;   // wave 0/1
    int g  = lane >> 5;          // node group 0/1 within wave
    int sg = (lane >> 4) & 1;    // edge parity sub-group
    int cc = (lane & 15) * 4;    // channel base (half4)
    int q = lane >> 4;           // mfma quad
    int c = lane & 15;           // mfma col
    int lane32 = lane & 31;
    int n0 = blockIdx.x * 16;
    const half4 z4 = {(_Float16)0, (_Float16)0, (_Float16)0, (_Float16)0};

    // stage ctab16 into LDS: 7680B = 480 x int4, 128 threads
    for (int i = threadIdx.x; i < 480; i += 128)
        ((int4*)sC)[i] = ((const int4*)ctab16)[i];

    // B fragments for this wave's two column-quadrants (pre-permuted, coalesced)
    const half8* wf = (const half8*)W16f;
    half8 bf[2][2];
    #pragma unroll
    for (int t = 0; t < 2; ++t) {
        bf[t][0] = wf[((wv * 2 + t) * 2 + 0) * 64 + lane];
        bf[t][1] = wf[((wv * 2 + t) * 2 + 1) * 64 + lane];
    }
    __syncthreads();   // sC ready

    // ---- phase 1: aggregation, one node per 32-lane group, 4 nodes per group ----
    #pragma unroll 1
    for (int i = 0; i < 4; ++i) {
        int r_loc = wv * 8 + g * 4 + i;      // sA row 0..15
        int n = n0 + r_loc;
        int beg = rp[n], end = rp[n + 1];
        int deg = end - beg;
        half4 sv = *(const half4*)(h16 + (size_t)n * 64 + cc);   // self (early issue)
        float ax = 0.f, ay = 0.f, az = 0.f, aw = 0.f;
        #pragma unroll 1
        for (int base = beg; base < end; base += 32) {
            int idx = base + lane32;
            idx = idx < end ? idx : end - 1;          // clamp (unused lanes)
            unsigned int rl = edges[idx];             // ONE coalesced record load
            int m = end - base; if (m > 32) m = 32;
            int t = 0;
            for (; t + 8 <= m; t += 8) {   // 8 edges: sub-group sg takes t+2u+sg
                unsigned int r[4];
                #pragma unroll
                for (int u = 0; u < 4; ++u)
                    r[u] = __shfl(rl, (g << 5) + t + 2 * u + sg, 64);
                half4 hh[4], tt[4];
                #pragma unroll
                for (int u = 0; u < 4; ++u) {
                    hh[u] = *(const half4*)(h16 + (size_t)(r[u] & 0x1FFFF) * 64 + cc);
                    tt[u] = *(const half4*)(sC + ((r[u] >> 17) & 63) * 64 + cc);
                }
                #pragma unroll
                for (int u = 0; u < 4; ++u) {
                    half4 mm = __builtin_elementwise_max(hh[u] + tt[u], z4);  // pk ops
                    ax += (float)mm[0]; ay += (float)mm[1];
                    az += (float)mm[2]; aw += (float)mm[3];
                }
            }
            for (; t < m; t += 2) {        // masked tail: 1 edge per sub-group/iter
                int e0 = t + sg;
                bool v0 = e0 < m;
                unsigned int r0 = __shfl(rl, (g << 5) + (v0 ? e0 : 0), 64);
                half4 h0 = *(const half4*)(h16 + (size_t)(r0 & 0x1FFFF) * 64 + cc);
                half4 t0 = *(const half4*)(sC + ((r0 >> 17) & 63) * 64 + cc);
                half4 m0 = __builtin_elementwise_max(h0 + t0, z4);
                if (v0) {
                    ax += (float)m0[0]; ay += (float)m0[1];
                    az += (float)m0[2]; aw += (float)m0[3];
                }
            }
        }
        // reduce across sub-groups (lane bit 4); replicates
        ax += __shfl_xor(ax, 16, 64); ay += __shfl_xor(ay, 16, 64);
        az += __shfl_xor(az, 16, 64); aw += __shfl_xor(aw, 16, 64);
        float ed = (float)deg * EPS_GEN;
        ax += (float)sv[0] + ed; ay += (float)sv[1] + ed;
        az += (float)sv[2] + ed; aw += (float)sv[3] + ed;
        if (sg == 0) {
            half4 pk;
            pk[0] = (_Float16)ax; pk[1] = (_Float16)ay;
            pk[2] = (_Float16)az; pk[3] = (_Float16)aw;
            *(half4*)(&sA[r_loc * 64 + cc]) = pk;
        }
    }
    __syncthreads();   // cross-wave: both waves' sA rows must be visible

    // ---- phase 2: MFMA (each wave: all 16 rows x its 32 columns) ----
    half8 af0 = *(const half8*)(sA + c * 64 + q * 8);         // kh=0
    half8 af1 = *(const half8*)(sA + c * 64 + 32 + q * 8);    // kh=1
    float4v d[2];
    #pragma unroll
    for (int t = 0; t < 2; ++t) {
        d[t] = (float4v){0.f, 0.f, 0.f, 0.f};
        d[t] = __builtin_amdgcn_mfma_f32_16x16x32_f16(af0, bf[t][0], d[t], 0, 0, 0);
        d[t] = __builtin_amdgcn_mfma_f32_16x16x32_f16(af1, bf[t][1], d[t], 0, 0, 0);
    }

    // ---- epilogue: bias + residual + store + stats partials ----
    float ps[2], pq[2];
    #pragma unroll
    for (int t = 0; t < 2; ++t) { ps[t] = 0.f; pq[t] = 0.f; }
    #pragma unroll
    for (int t = 0; t < 2; ++t) {
        int tg = wv * 2 + t;
        float bz = bvec[tg * 16 + c];
        #pragma unroll
        for (int r = 0; r < 4; ++r) {
            int row = n0 + q * 4 + r;
            float val = d[t][r] + bz;
            size_t off = (size_t)row * 64 + tg * 16 + c;
            if (res) val += res[off];
            out[off] = val;
            ps[t] += val;
            pq[t] = fmaf(val, val, pq[t]);
        }
    }
    #pragma unroll
    for (int t = 0; t < 2; ++t) {
        ps[t] += __shfl_xor(ps[t], 16, 64); ps[t] += __shfl_xor(ps[t], 32, 64);
        pq[t] += __shfl_xor(pq[t], 16, 64); pq[t] += __shfl_xor(pq[t], 32, 64);
    }
    float* sp = statsPart + ((blockIdx.x * 2 + wv) & (SLOTS - 1)) * 128;
    if (lane < 16) {
        #pragma unroll
        for (int t = 0; t < 2; ++t) {
            int tg = wv * 2 + t;
            atomicAdd(&sp[tg * 16 + lane], ps[t]);
            atomicAdd(&sp[64 + tg * 16 + lane], pq[t]);
        }
    }
}

// ---------------- BN / pooling ----------------

// h16 = fp16(relu(bn(h))); vt[batch[n]] += run-length aggregated; chunk=8 nodes/wave.
// Stats fold done per-block with ALL 256 threads (strided, coalesced lines).
__global__ void k_bn_relu_vt2(const float* __restrict__ h, const float* __restrict__ spart,
                              const float* __restrict__ gamma, const float* __restrict__ beta,
                              const int* __restrict__ batch,
                              _Float16* __restrict__ h16, float* __restrict__ vt) {
    __shared__ float sTmp[256];
    __shared__ float sMS[128];
    {
        int ch = threadIdx.x & 127, hf = threadIdx.x >> 7;
        float a = 0.f;
        #pragma unroll 8
        for (int i = hf; i < SLOTS; i += 2) a += spart[i * 128 + ch];
        sTmp[threadIdx.x] = a;
    }
    __syncthreads();
    if (threadIdx.x < 64) {
        int c = threadIdx.x;
        float s = sTmp[c] + sTmp[128 + c];
        float q = sTmp[64 + c] + sTmp[192 + c];
        float mu = s * (1.f / NN);
        float var = q * (1.f / NN) - mu * mu;
        sMS[c] = mu;
        sMS[64 + c] = rsqrtf(var + EPS_BN);
    }
    __syncthreads();
    int lane = threadIdx.x & 63;
    int w = blockIdx.x * 4 + (threadIdx.x >> 6);
    int n0 = w * 8;
    if (n0 >= NN) return;
    int n1 = min(n0 + 8, NN);
    float mu = sMS[lane];
    float inv = sMS[64 + lane] * gamma[lane];
    float bet = beta[lane];
    float acc = 0.f;
    int gcur = batch[n0];
    for (int n = n0; n < n1; ++n) {
        float v = fmaxf((h[(size_t)n * 64 + lane] - mu) * inv + bet, 0.f);
        h16[(size_t)n * 64 + lane] = (_Float16)v;
        int g = batch[n];
        if (g != gcur) {
            atomicAdd(&vt[(size_t)gcur * 64 + lane], acc);
            acc = 0.f; gcur = g;
        }
        acc += v;
    }
    atomicAdd(&vt[(size_t)gcur * 64 + lane], acc);
}

// VN GEMM over 512 rows (32 blocks, 4 rows/wave): out = (bnrelu?(in) + add) @ W + b
// (R7 lesson: keep the two-dispatch 128-wave form; 1-block fusion was 186us/layer)
__global__ void k_vn_gemm(float* __restrict__ in, int clear_in,
                          const float* in_stats, const float* in_g, const float* in_be,
                          const float* addmat, const float* add_stats,
                          const float* add_g, const float* add_be,
                          const float* addvec,
                          const float* __restrict__ W, const float* __restrict__ bvec,
                          float* __restrict__ out, float* __restrict__ out_stats) {
    __shared__ float sW[4096];
    __shared__ float sRed[2][4][64];
    for (int i = threadIdx.x; i < 4096; i += 256) sW[i] = W[i];
    __syncthreads();
    int lane = threadIdx.x & 63, wv = threadIdx.x >> 6;
    int w = blockIdx.x * 4 + wv;          // 128 waves, 4 rows each
    float imu = 0.f, iinv = 0.f, ibe = 0.f;
    if (in_stats) {
        float mu = in_stats[lane] * (1.f / GG);
        float var = in_stats[64 + lane] * (1.f / GG) - mu * mu;
        imu = mu; iinv = rsqrtf(var + EPS_BN) * in_g[lane]; ibe = in_be[lane];
    }
    float amu = 0.f, ainv = 0.f, abe = 0.f;
    if (addmat && add_stats) {
        float mu = add_stats[lane] * (1.f / GG);
        float var = add_stats[64 + lane] * (1.f / GG) - mu * mu;
        amu = mu; ainv = rsqrtf(var + EPS_BN) * add_g[lane]; abe = add_be[lane];
    }
    float av_const = addvec ? addvec[lane] : 0.f;
    float psum = 0.f, psq = 0.f;
    for (int r = w * 4; r < w * 4 + 4; ++r) {
        float va = in[r * 64 + lane];
        if (clear_in) in[r * 64 + lane] = 0.f;
        if (in_stats) va = fmaxf((va - imu) * iinv + ibe, 0.f);
        if (addmat) va += fmaxf((addmat[r * 64 + lane] - amu) * ainv + abe, 0.f);
        va += av_const;
        float acc = bvec[lane];
        #pragma unroll
        for (int k = 0; k < 64; ++k)
            acc = fmaf(__shfl(va, k, 64), sW[k * 64 + lane], acc);
        out[r * 64 + lane] = acc;
        psum += acc; psq = fmaf(acc, acc, psq);
    }
    sRed[0][wv][lane] = psum;
    sRed[1][wv][lane] = psq;
    __syncthreads();
    if (threadIdx.x < 64) {
        float s = 0.f, q = 0.f;
        #pragma unroll
        for (int i = 0; i < 4; ++i) { s += sRed[0][i][threadIdx.x]; q += sRed[1][i][threadIdx.x]; }
        atomicAdd(&out_stats[threadIdx.x], s);
        atomicAdd(&out_stats[64 + threadIdx.x], q);
    }
}

// h16[n] += bnrelu(t2)[batch[n]]  (16 threads/node, half4/float4 wide)
__global__ void k_addvn16(_Float16* __restrict__ h16, const float* __restrict__ t2,
                          const float* __restrict__ stats,
                          const float* __restrict__ g2, const float* __restrict__ be2,
                          const int* __restrict__ batch) {
    int tid = blockIdx.x * blockDim.x + threadIdx.x;
    int n = tid >> 4, p = tid & 15;
    if (n >= NN) return;
    int c0 = p * 4;
    float mu[4], iv[4], be[4];
    #pragma unroll
    for (int k = 0; k < 4; ++k) {
        int ci = c0 + k;
        float m = stats[ci] * (1.f / GG);
        float v = stats[64 + ci] * (1.f / GG) - m * m;
        mu[k] = m;
        iv[k] = rsqrtf(v + EPS_BN) * g2[ci];
        be[k] = be2[ci];
    }
    int g = batch[n];
    float4 t = *(const float4*)(t2 + (size_t)g * 64 + c0);
    float tv[4] = {t.x, t.y, t.z, t.w};
    half4 hv = *(half4*)(h16 + (size_t)n * 64 + c0);
    half4 o;
    #pragma unroll
    for (int k = 0; k < 4; ++k) {
        float a = fmaxf((tv[k] - mu[k]) * iv[k] + be[k], 0.f);
        o[k] = (_Float16)((float)hv[k] + a);
    }
    *(half4*)(h16 + (size_t)n * 64 + c0) = o;
}

// final BN + mean-pool, run-length aggregated; chunk=16; stats fold inlined
__global__ void k_pool2(const float* __restrict__ h, const float* __restrict__ spart,
                        const float* __restrict__ gamma, const float* __restrict__ beta,
                        const int* __restrict__ batch,
                        float* __restrict__ out, float* __restrict__ cnt) {
    __shared__ float sTmp[256];
    __shared__ float sMS[128];
    {
        int ch = threadIdx.x & 127, hf = threadIdx.x >> 7;
        float a = 0.f;
        #pragma unroll 8
        for (int i = hf; i < SLOTS; i += 2) a += spart[i * 128 + ch];
        sTmp[threadIdx.x] = a;
    }
    __syncthreads();
    if (threadIdx.x < 64) {
        int c = threadIdx.x;
        float s = sTmp[c] + sTmp[128 + c];
        float q = sTmp[64 + c] + sTmp[192 + c];
        float mu = s * (1.f / NN);
        float var = q * (1.f / NN) - mu * mu;
        sMS[c] = mu;
        sMS[64 + c] = rsqrtf(var + EPS_BN);
    }
    __syncthreads();
    int lane = threadIdx.x & 63;
    int w = blockIdx.x * 4 + (threadIdx.x >> 6);
    int n0 = w * 16;
    if (n0 >= NN) return;
    int n1 = min(n0 + 16, NN);
    float mu = sMS[lane];
    float inv = sMS[64 + lane] * gamma[lane];
    float bet = beta[lane];
    float acc = 0.f;
    int run = 0;
    int gcur = batch[n0];
    for (int n = n0; n < n1; ++n) {
        float v = (h[(size_t)n * 64 + lane] - mu) * inv + bet;
        int g = batch[n];
        if (g != gcur) {
            atomicAdd(&out[(size_t)gcur * 64 + lane], acc);
            if (lane == 0) atomicAdd(&cnt[gcur], (float)run);
            acc = 0.f; run = 0; gcur = g;
        }
        acc += v; run++;
    }
    atomicAdd(&out[(size_t)gcur * 64 + lane], acc);
    if (lane == 0) atomicAdd(&cnt[gcur], (float)run);
}

__global__ void k_div(float* __restrict__ out, const float* __restrict__ cnt) {
    int tid = blockIdx.x * blockDim.x + threadIdx.x;
    if (tid >= GH) return;
    out[tid] /= fmaxf(cnt[tid >> 6], 1.0f);
}

extern "C" void kernel_launch(void* const* d_in, const int* in_sizes, int n_in,
                              void* d_out, int out_size, void* d_ws, size_t ws_size,
                              hipStream_t stream) {
    const float* atom_table = (const float*)d_in[0];
    const float* bond_table = (const float*)d_in[1];
    const float* vn0   = (const float*)d_in[2];
    const float* gcn_W = (const float*)d_in[3];
    const float* gcn_b = (const float*)d_in[4];
    const float* ng    = (const float*)d_in[5];
    const float* nb    = (const float*)d_in[6];
    const float* vn_W1 = (const float*)d_in[7];
    const float* vn_b1 = (const float*)d_in[8];
    const float* vn_g1 = (const float*)d_in[9];
    const float* vn_be1= (const float*)d_in[10];
    const float* vn_W2 = (const float*)d_in[11];
    const float* vn_b2 = (const float*)d_in[12];
    const float* vn_g2 = (const float*)d_in[13];
    const float* vn_be2= (const float*)d_in[14];
    const int* x          = (const int*)d_in[15];
    const int* edge_index = (const int*)d_in[16];
    const int* edge_attr  = (const int*)d_in[17];
    const int* batch      = (const int*)d_in[18];

    float* ws = (float*)d_ws;
    float* hB   = ws;                                 // NH fp32 (running h)
    _Float16* h16 = (_Float16*)(ws + (size_t)NH);     // NH fp16 (gather source)
    float* vt   = ws + (size_t)NH + NH / 2;           // GH
    float* t1   = vt + GH;                            // GH
    float* t2   = t1 + GH;                            // GH
    float* convStatsP = t2 + GH;                      // 7 * SLOTS * 128
    float* msAll      = convStatsP + 7 * SLOTS * 128; // 7 * 128 (layout keep)
    float* vn1Stats   = msAll + 7 * 128;              // 6*128
    float* vn2Stats   = vn1Stats + 6 * 128;           // 6*128
    float* cnt    = vn2Stats + 6 * 128;               // GG
    _Float16* ctab16 = (_Float16*)(cnt + GG);         // 60*64 fp16
    _Float16* W16f   = ctab16 + 60 * 64;              // 7*4096 fp16 (fragment order)
    int*   rp     = (int*)(W16f + LL * 4096);         // NN+1 (+1 pad -> even offsets)
    int*   cur    = rp + (NN + 2);                    // NN/4 words (byte-packed counts)
    int*   part   = cur + NN;                         // 128
    unsigned int* edges = (unsigned int*)(part + 128);  // EE
    // recs is CSR-build scratch only; alias the h16 region (atom_enc runs after fill2)
    unsigned int* recs = (unsigned int*)h16;            // EE (4MB <= 12.8MB h16)

    const int blkN = NH / 256;               // 25000
    const int blkG = (GH + 255) / 256;       // 128
    const int blkE = (EE + 255) / 256;       // 3907
    const int blkRL = ((NN + 7) / 8 + 3) / 4;   // 3125
    const int blkPL = ((NN + 15) / 16 + 3) / 4; // 1563
    const int blkAV = (NN * 16) / 256;       // 6250
    const int blkPR = (LL * 4096 + 60 * 64 + 255) / 256;  // 127
    float* outp = (float*)d_out;

    // ---- CSR build first (recs aliases h16; must finish before k_atom_enc) ----
    hipMemsetAsync(cur, 0, (size_t)(NN / 4) * 4, stream);    // 100KB byte-packed
    k_count2<<<blkE, 256, 0, stream>>>(edge_index, edge_attr, (unsigned int*)cur, recs);
    k_scan1<<<SCAN_BLKS, 256, 0, stream>>>((const unsigned int*)cur, rp, part);
    k_scan2<<<1, 128, 0, stream>>>(part);
    k_scan3<<<(NN + 255) / 256, 256, 0, stream>>>(rp, part);
    k_fill2<<<blkE, 256, 0, stream>>>(edge_index, recs, rp, edges);

    k_atom_enc<<<blkN, 256, 0, stream>>>(atom_table, vn0, x, h16);
    k_prep<<<blkPR, 256, 0, stream>>>(gcn_W, bond_table, W16f, ctab16);
    hipMemsetAsync(convStatsP, 0, (7 * SLOTS * 128 + 7 * 128 + 12 * 128) * 4, stream);
    hipMemsetAsync(vt, 0, (size_t)GH * 4, stream);

    // ---- layer 0: hB = (h16 + agg(h16)) @ W0 + b0 ----
    k_conv_mfma<<<CONV_BLOCKS, 128, 0, stream>>>(h16, nullptr, rp, edges, ctab16, W16f,
                                                 gcn_b, hB, convStatsP);

    for (int l = 1; l < LL; ++l) {
        // h16 = relu(bn(hB)) (stats folded in-block); vt = segment_sum(h16)
        k_bn_relu_vt2<<<blkRL, 256, 0, stream>>>(hB, convStatsP + (size_t)(l - 1) * SLOTS * 128,
                                                 ng + (size_t)(l - 1) * HH,
                                                 nb + (size_t)(l - 1) * HH, batch, h16, vt);
        // t1 = (vt + vn_prev) @ W1 + b1 ; vn_prev = l==1 ? vn0 : bnrelu(t2, vn2Stats[l-2])
        if (l == 1)
            k_vn_gemm<<<32, 256, 0, stream>>>(vt, 1, nullptr, nullptr, nullptr,
                                              nullptr, nullptr, nullptr, nullptr, vn0,
                                              vn_W1, vn_b1, t1, vn1Stats);
        else
            k_vn_gemm<<<32, 256, 0, stream>>>(vt, 1, nullptr, nullptr, nullptr,
                                              t2, vn2Stats + (size_t)(l - 2) * 128,
                                              vn_g2 + (size_t)(l - 2) * HH,
                                              vn_be2 + (size_t)(l - 2) * HH, nullptr,
                                              vn_W1 + (size_t)(l - 1) * 4096,
                                              vn_b1 + (size_t)(l - 1) * HH, t1,
                                              vn1Stats + (size_t)(l - 1) * 128);
        // t2 = bnrelu(t1) @ W2 + b2
        k_vn_gemm<<<32, 256, 0, stream>>>(t1, 0, vn1Stats + (size_t)(l - 1) * 128,
                                          vn_g1 + (size_t)(l - 1) * HH,
                                          vn_be1 + (size_t)(l - 1) * HH,
                                          nullptr, nullptr, nullptr, nullptr, nullptr,
                                          vn_W2 + (size_t)(l - 1) * 4096,
                                          vn_b2 + (size_t)(l - 1) * HH, t2,
                                          vn2Stats + (size_t)(l - 1) * 128);
        // h16 += bnrelu(t2)[batch]
        k_addvn16<<<blkAV, 256, 0, stream>>>(h16, t2, vn2Stats + (size_t)(l - 1) * 128,
                                             vn_g2 + (size_t)(l - 1) * HH,
                                             vn_be2 + (size_t)(l - 1) * HH, batch);

        k_conv_mfma<<<CONV_BLOCKS, 128, 0, stream>>>(h16, hB, rp, edges, ctab16,
                                                     W16f + (size_t)l * 4096,
                                                     gcn_b + (size_t)l * HH, hB,
                                                     convStatsP + (size_t)l * SLOTS * 128);
    }

    // ---- final BN + mean pool (stats fold inlined in k_pool2) ----
    hipMemsetAsync(outp, 0, (size_t)GH * 4, stream);
    hipMemsetAsync(cnt, 0, (size_t)GG * 4, stream);
    k_pool2<<<blkPL, 256, 0, stream>>>(hB, convStatsP + (size_t)6 * SLOTS * 128,
                                       ng + (size_t)6 * HH, nb + (size_t)6 * HH,
                                       batch, outp, cnt);
    k_div<<<blkG, 256, 0, stream>>>(outp, cnt);
}

// Round 9
// 761.452 us; speedup vs baseline: 2.2399x; 1.0356x over previous
//
#include <hip/hip_runtime.h>
#include <hip/hip_bf16.h>
#include <hip/hip_fp16.h>

#define NN 100000
#define EE 1000000
#define GG 512
#define HH 64
#define LL 7
#define NH (NN*HH)
#define GH (GG*HH)
#define EPS_GEN 1e-7f
#define EPS_BN 1e-5f
#define SCAN_BLKS 98   // ceil(NN/1024)
#define SLOTS 64
#define CONV_BLOCKS 6250   // 16 nodes per 128-thread (2-wave) block (R3/R6 proven shape)

typedef _Float16 half8  __attribute__((ext_vector_type(8)));
typedef _Float16 half4  __attribute__((ext_vector_type(4)));
typedef _Float16 half2v __attribute__((ext_vector_type(2)));
typedef float    float4v __attribute__((ext_vector_type(4)));

__device__ __constant__ int c_atom_off[9] = {0,119,124,136,148,158,164,170,172};

// h16[n][c] = fp16( vn0[c] + sum_f atom_table[x[n][f]+off_f][c] )
__global__ void k_atom_enc(const float* __restrict__ atom_table,
                           const float* __restrict__ vn0,
                           const int* __restrict__ x,
                           _Float16* __restrict__ h16) {
    int tid = blockIdx.x * blockDim.x + threadIdx.x;
    int n = tid >> 6, c = tid & 63;
    if (n >= NN) return;
    float acc = vn0[c];
    const int* xr = x + n * 9;
    #pragma unroll
    for (int f = 0; f < 9; ++f) acc += atom_table[(xr[f] + c_atom_off[f]) * HH + c];
    h16[tid] = (_Float16)acc;
}

// merged prep: W16f = fp16 conv weights pre-permuted into MFMA B-fragment order;
// ctab16 = fp16 combined bond table (c = a0 + 5*a1 + 30*a2)
__global__ void k_prep(const float* __restrict__ W, const float* __restrict__ bond,
                       _Float16* __restrict__ W16f, _Float16* __restrict__ ctab16) {
    int i = blockIdx.x * blockDim.x + threadIdx.x;
    if (i < LL * 4096) {
        int l = i / 4096, r = i % 4096;
        int j = r & 7, lane = (r >> 3) & 63, kh = (r >> 9) & 1, t = r >> 10;
        int q = (lane >> 4) & 3, c = lane & 15;
        W16f[i] = (_Float16)W[l * 4096 + (kh * 32 + q * 8 + j) * 64 + t * 16 + c];
    } else {
        int k = i - LL * 4096;
        if (k < 60 * 64) {
            int cmb = k >> 6, lane = k & 63;
            int a0 = cmb % 5, a1 = (cmb / 5) % 6, a2 = cmb / 30;
            ctab16[k] = (_Float16)(bond[a0 * 64 + lane] + bond[(5 + a1) * 64 + lane]
                                   + bond[(11 + a2) * 64 + lane]);
        }
    }
}

// ---------------- CSR build ----------------
// Int histogram (R8 lesson: byte-packing was null on WRITE — the ~31MB stream is
// per-atomic write-through, not line footprint — and packed words contended +6us).
// atomicAdd return IS the within-dst rank. rec = src(17) | combo(6)<<17 | rank(9)<<23.
__global__ void k_count2(const int* __restrict__ edge_index, const int* __restrict__ edge_attr,
                         int* __restrict__ cur, unsigned int* __restrict__ recs) {
    int e = blockIdx.x * blockDim.x + threadIdx.x;
    if (e >= EE) return;
    int src = edge_index[e];
    int dst = edge_index[EE + e];
    int combo = edge_attr[e * 3] + 5 * edge_attr[e * 3 + 1] + 30 * edge_attr[e * 3 + 2];
    unsigned int rank = (unsigned int)atomicAdd(&cur[dst], 1);
    recs[e] = (unsigned int)src | ((unsigned int)combo << 17) | (rank << 23);
}

__global__ void k_scan1(const int* __restrict__ cnt, int* __restrict__ rp, int* __restrict__ part) {
    __shared__ int s[256];
    int t = threadIdx.x, blk = blockIdx.x;
    int base = blk * 1024 + t * 4;
    int v0 = 0, v1 = 0, v2 = 0, v3 = 0;
    if (base + 3 < NN) {
        int4 q = *(const int4*)(cnt + base);
        v0 = q.x; v1 = q.y; v2 = q.z; v3 = q.w;
    } else {
        if (base + 0 < NN) v0 = cnt[base + 0];
        if (base + 1 < NN) v1 = cnt[base + 1];
        if (base + 2 < NN) v2 = cnt[base + 2];
        if (base + 3 < NN) v3 = cnt[base + 3];
    }
    int s4 = v0 + v1 + v2 + v3;
    s[t] = s4;
    __syncthreads();
    for (int off = 1; off < 256; off <<= 1) {
        int x = (t >= off) ? s[t - off] : 0;
        __syncthreads();
        s[t] += x;
        __syncthreads();
    }
    int excl = s[t] - s4;
    if (t == 255) part[blk] = s[255];
    if (base + 0 < NN) rp[base + 0] = excl;
    if (base + 1 < NN) rp[base + 1] = excl + v0;
    if (base + 2 < NN) rp[base + 2] = excl + v0 + v1;
    if (base + 3 < NN) rp[base + 3] = excl + v0 + v1 + v2;
}

// R9: scan2 folded in — each block re-reduces the <=98 raw partials in LDS
// (removes one dependent tiny dispatch from the critical path).
__global__ void k_scan3(int* __restrict__ rp, const int* __restrict__ part) {
    __shared__ int s[256];
    int p = blockIdx.x >> 2;                 // this block's 1024-chunk index (<=97)
    s[threadIdx.x] = (threadIdx.x < p) ? part[threadIdx.x] : 0;
    __syncthreads();
    for (int off = 128; off > 0; off >>= 1) {
        if (threadIdx.x < off) s[threadIdx.x] += s[threadIdx.x + off];
        __syncthreads();
    }
    int pre = s[0];                          // exclusive prefix of partial p
    int i = blockIdx.x * 256 + threadIdx.x;
    if (i < NN) rp[i] += pre;
    if (i == 0) rp[NN] = EE;
}

// atomic-free scatter: slot = rp[dst] + rank (rank from the packed record)
__global__ void k_fill2(const int* __restrict__ edge_index, const unsigned int* __restrict__ recs,
                        const int* __restrict__ rp, unsigned int* __restrict__ edges) {
    int e = blockIdx.x * blockDim.x + threadIdx.x;
    if (e >= EE) return;
    unsigned int rec = recs[e];
    int dst = edge_index[EE + e];
    edges[rp[dst] + (rec >> 23)] = rec & 0x7FFFFFu;
}

// ---------------- conv: gather/aggregate -> MFMA GEMM (+res) + stats ----------------
// R9 gather restructure: 8 lanes x 16B (half8) per edge — half the vmem instruction
// count at identical bytes, 4 edges' loads issued back-to-back per round.
// Per 32-lane node group: e_idx = (lane&31)>>3 picks the edge slot, ch8 = (lane&7)*8
// the channel octet. Cross-slot reduce = shfl_xor 8 then 16. B-fragments + self row
// load moved AFTER phase 1 to stay <=64 VGPR (8 waves/EU).
// NOTE (R1): no extra per-edge gather streams. (R4/R5): no tickets / indep waves.
// (R7): never 1-block fusions. (R12): no NT hints, no fences.
__global__ __launch_bounds__(128, 8) void k_conv_mfma(
        const _Float16* __restrict__ h16, const float* res,
        const int* __restrict__ rp, const unsigned int* __restrict__ edges,
        const _Float16* __restrict__ ctab16, const _Float16* __restrict__ W16f,
        const float* __restrict__ bvec,
        float* __restrict__ out, float* __restrict__ statsPart) {
    __shared__ __align__(16) _Float16 sA[16 * 64];   // 2KB accumulator tile
    __shared__ __align__(16) _Float16 sC[60 * 64];   // 7.5KB combined bond table
    int lane = threadIdx.x & 63;
    int wv = threadIdx.x >> 6;   // wave 0/1
    int g  = lane >> 5;          // node group 0/1 within wave
    int lane32 = lane & 31;
    int e_idx = lane32 >> 3;     // edge slot 0..3
    int ch8 = (lane32 & 7) * 8;  // channel octet base
    int q = lane >> 4;           // mfma quad
    int c = lane & 15;           // mfma col
    int n0 = blockIdx.x * 16;
    const half8 z8 = {(_Float16)0, (_Float16)0, (_Float16)0, (_Float16)0,
                      (_Float16)0, (_Float16)0, (_Float16)0, (_Float16)0};

    // stage ctab16 into LDS: 7680B = 480 x int4, 128 threads
    for (int i = threadIdx.x; i < 480; i += 128)
        ((int4*)sC)[i] = ((const int4*)ctab16)[i];
    __syncthreads();   // sC ready

    // ---- phase 1: aggregation, one node per 32-lane group, 4 nodes per group ----
    #pragma unroll 1
    for (int i = 0; i < 4; ++i) {
        int r_loc = wv * 8 + g * 4 + i;      // sA row 0..15
        int n = n0 + r_loc;
        int beg = rp[n], end = rp[n + 1];
        int deg = end - beg;
        float acc[8];
        #pragma unroll
        for (int j = 0; j < 8; ++j) acc[j] = 0.f;
        #pragma unroll 1
        for (int base = beg; base < end; base += 32) {
            int idx = base + lane32;
            idx = idx < end ? idx : end - 1;          // clamp (unused lanes)
            unsigned int rl = edges[idx];             // ONE coalesced record load
            int m = end - base; if (m > 32) m = 32;
            #pragma unroll 1
            for (int t = 0; t < m; t += 16) {         // 16 edges: slot e_idx does 4
                unsigned int r[4];
                bool vld[4];
                #pragma unroll
                for (int k = 0; k < 4; ++k) {
                    int e = t + k * 4 + e_idx;
                    vld[k] = e < m;
                    r[k] = __shfl(rl, (g << 5) + (vld[k] ? e : 0), 64);
                }
                half8 hh[4], tt[4];
                #pragma unroll
                for (int k = 0; k < 4; ++k) {
                    hh[k] = *(const half8*)(h16 + (size_t)(r[k] & 0x1FFFF) * 64 + ch8);
                    tt[k] = *(const half8*)(sC + ((r[k] >> 17) & 63) * 64 + ch8);
                }
                #pragma unroll
                for (int k = 0; k < 4; ++k) {
                    half8 mm = __builtin_elementwise_max(hh[k] + tt[k], z8);  // pk ops
                    if (vld[k]) {
                        #pragma unroll
                        for (int j = 0; j < 8; ++j) acc[j] += (float)mm[j];
                    }
                }
            }
        }
        // reduce across edge slots (lane bits 3 and 4); replicates
        #pragma unroll
        for (int j = 0; j < 8; ++j) {
            acc[j] += __shfl_xor(acc[j], 8, 64);
            acc[j] += __shfl_xor(acc[j], 16, 64);
        }
        half8 sv = *(const half8*)(h16 + (size_t)n * 64 + ch8);  // self row
        float ed = (float)deg * EPS_GEN;
        half8 pk;
        #pragma unroll
        for (int j = 0; j < 8; ++j) pk[j] = (_Float16)(acc[j] + (float)sv[j] + ed);
        if (e_idx == 0)
            *(half8*)(&sA[r_loc * 64 + ch8]) = pk;
    }

    // B fragments for this wave's two column-quadrants (pre-permuted, coalesced);
    // loaded after phase 1 to keep aggregation-loop VGPR pressure <=64.
    const half8* wf = (const half8*)W16f;
    half8 bf[2][2];
    #pragma unroll
    for (int t = 0; t < 2; ++t) {
        bf[t][0] = wf[((wv * 2 + t) * 2 + 0) * 64 + lane];
        bf[t][1] = wf[((wv * 2 + t) * 2 + 1) * 64 + lane];
    }
    __syncthreads();   // cross-wave: both waves' sA rows must be visible

    // ---- phase 2: MFMA (each wave: all 16 rows x its 32 columns) ----
    half8 af0 = *(const half8*)(sA + c * 64 + q * 8);         // kh=0
    half8 af1 = *(const half8*)(sA + c * 64 + 32 + q * 8);    // kh=1
    float4v d[2];
    #pragma unroll
    for (int t = 0; t < 2; ++t) {
        d[t] = (float4v){0.f, 0.f, 0.f, 0.f};
        d[t] = __builtin_amdgcn_mfma_f32_16x16x32_f16(af0, bf[t][0], d[t], 0, 0, 0);
        d[t] = __builtin_amdgcn_mfma_f32_16x16x32_f16(af1, bf[t][1], d[t], 0, 0, 0);
    }

    // ---- epilogue: bias + residual + store + stats partials ----
    float ps[2], pq[2];
    #pragma unroll
    for (int t = 0; t < 2; ++t) { ps[t] = 0.f; pq[t] = 0.f; }
    #pragma unroll
    for (int t = 0; t < 2; ++t) {
        int tg = wv * 2 + t;
        float bz = bvec[tg * 16 + c];
        #pragma unroll
        for (int r = 0; r < 4; ++r) {
            int row = n0 + q * 4 + r;
            float val = d[t][r] + bz;
            size_t off = (size_t)row * 64 + tg * 16 + c;
            if (res) val += res[off];
            out[off] = val;
            ps[t] += val;
            pq[t] = fmaf(val, val, pq[t]);
        }
    }
    #pragma unroll
    for (int t = 0; t < 2; ++t) {
        ps[t] += __shfl_xor(ps[t], 16, 64); ps[t] += __shfl_xor(ps[t], 32, 64);
        pq[t] += __shfl_xor(pq[t], 16, 64); pq[t] += __shfl_xor(pq[t], 32, 64);
    }
    float* sp = statsPart + ((blockIdx.x * 2 + wv) & (SLOTS - 1)) * 128;
    if (lane < 16) {
        #pragma unroll
        for (int t = 0; t < 2; ++t) {
            int tg = wv * 2 + t;
            atomicAdd(&sp[tg * 16 + lane], ps[t]);
            atomicAdd(&sp[64 + tg * 16 + lane], pq[t]);
        }
    }
}

// ---------------- BN / pooling ----------------

// h16 = fp16(relu(bn(h))); vt[batch[n]] += run-length aggregated; chunk=8 nodes/wave.
// Stats fold done per-block with ALL 256 threads (strided, coalesced lines).
__global__ void k_bn_relu_vt2(const float* __restrict__ h, const float* __restrict__ spart,
                              const float* __restrict__ gamma, const float* __restrict__ beta,
                              const int* __restrict__ batch,
                              _Float16* __restrict__ h16, float* __restrict__ vt) {
    __shared__ float sTmp[256];
    __shared__ float sMS[128];
    {
        int ch = threadIdx.x & 127, hf = threadIdx.x >> 7;
        float a = 0.f;
        #pragma unroll 8
        for (int i = hf; i < SLOTS; i += 2) a += spart[i * 128 + ch];
        sTmp[threadIdx.x] = a;
    }
    __syncthreads();
    if (threadIdx.x < 64) {
        int c = threadIdx.x;
        float s = sTmp[c] + sTmp[128 + c];
        float q = sTmp[64 + c] + sTmp[192 + c];
        float mu = s * (1.f / NN);
        float var = q * (1.f / NN) - mu * mu;
        sMS[c] = mu;
        sMS[64 + c] = rsqrtf(var + EPS_BN);
    }
    __syncthreads();
    int lane = threadIdx.x & 63;
    int w = blockIdx.x * 4 + (threadIdx.x >> 6);
    int n0 = w * 8;
    if (n0 >= NN) return;
    int n1 = min(n0 + 8, NN);
    float mu = sMS[lane];
    float inv = sMS[64 + lane] * gamma[lane];
    float bet = beta[lane];
    float acc = 0.f;
    int gcur = batch[n0];
    for (int n = n0; n < n1; ++n) {
        float v = fmaxf((h[(size_t)n * 64 + lane] - mu) * inv + bet, 0.f);
        h16[(size_t)n * 64 + lane] = (_Float16)v;
        int g = batch[n];
        if (g != gcur) {
            atomicAdd(&vt[(size_t)gcur * 64 + lane], acc);
            acc = 0.f; gcur = g;
        }
        acc += v;
    }
    atomicAdd(&vt[(size_t)gcur * 64 + lane], acc);
}

// VN GEMM over 512 rows (32 blocks, 4 rows/wave): out = (bnrelu?(in) + add) @ W + b
// (R7 lesson: keep the two-dispatch 128-wave form; 1-block fusion was 186us/layer)
__global__ void k_vn_gemm(float* __restrict__ in, int clear_in,
                          const float* in_stats, const float* in_g, const float* in_be,
                          const float* addmat, const float* add_stats,
                          const float* add_g, const float* add_be,
                          const float* addvec,
                          const float* __restrict__ W, const float* __restrict__ bvec,
                          float* __restrict__ out, float* __restrict__ out_stats) {
    __shared__ float sW[4096];
    __shared__ float sRed[2][4][64];
    for (int i = threadIdx.x; i < 4096; i += 256) sW[i] = W[i];
    __syncthreads();
    int lane = threadIdx.x & 63, wv = threadIdx.x >> 6;
    int w = blockIdx.x * 4 + wv;          // 128 waves, 4 rows each
    float imu = 0.f, iinv = 0.f, ibe = 0.f;
    if (in_stats) {
        float mu = in_stats[lane] * (1.f / GG);
        float var = in_stats[64 + lane] * (1.f / GG) - mu * mu;
        imu = mu; iinv = rsqrtf(var + EPS_BN) * in_g[lane]; ibe = in_be[lane];
    }
    float amu = 0.f, ainv = 0.f, abe = 0.f;
    if (addmat && add_stats) {
        float mu = add_stats[lane] * (1.f / GG);
        float var = add_stats[64 + lane] * (1.f / GG) - mu * mu;
        amu = mu; ainv = rsqrtf(var + EPS_BN) * add_g[lane]; abe = add_be[lane];
    }
    float av_const = addvec ? addvec[lane] : 0.f;
    float psum = 0.f, psq = 0.f;
    for (int r = w * 4; r < w * 4 + 4; ++r) {
        float va = in[r * 64 + lane];
        if (clear_in) in[r * 64 + lane] = 0.f;
        if (in_stats) va = fmaxf((va - imu) * iinv + ibe, 0.f);
        if (addmat) va += fmaxf((addmat[r * 64 + lane] - amu) * ainv + abe, 0.f);
        va += av_const;
        float acc = bvec[lane];
        #pragma unroll
        for (int k = 0; k < 64; ++k)
            acc = fmaf(__shfl(va, k, 64), sW[k * 64 + lane], acc);
        out[r * 64 + lane] = acc;
        psum += acc; psq = fmaf(acc, acc, psq);
    }
    sRed[0][wv][lane] = psum;
    sRed[1][wv][lane] = psq;
    __syncthreads();
    if (threadIdx.x < 64) {
        float s = 0.f, q = 0.f;
        #pragma unroll
        for (int i = 0; i < 4; ++i) { s += sRed[0][i][threadIdx.x]; q += sRed[1][i][threadIdx.x]; }
        atomicAdd(&out_stats[threadIdx.x], s);
        atomicAdd(&out_stats[64 + threadIdx.x], q);
    }
}

// h16[n] += bnrelu(t2)[batch[n]]  (16 threads/node, half4/float4 wide)
__global__ void k_addvn16(_Float16* __restrict__ h16, const float* __restrict__ t2,
                          const float* __restrict__ stats,
                          const float* __restrict__ g2, const float* __restrict__ be2,
                          const int* __restrict__ batch) {
    int tid = blockIdx.x * blockDim.x + threadIdx.x;
    int n = tid >> 4, p = tid & 15;
    if (n >= NN) return;
    int c0 = p * 4;
    float mu[4], iv[4], be[4];
    #pragma unroll
    for (int k = 0; k < 4; ++k) {
        int ci = c0 + k;
        float m = stats[ci] * (1.f / GG);
        float v = stats[64 + ci] * (1.f / GG) - m * m;
        mu[k] = m;
        iv[k] = rsqrtf(v + EPS_BN) * g2[ci];
        be[k] = be2[ci];
    }
    int g = batch[n];
    float4 t = *(const float4*)(t2 + (size_t)g * 64 + c0);
    float tv[4] = {t.x, t.y, t.z, t.w};
    half4 hv = *(half4*)(h16 + (size_t)n * 64 + c0);
    half4 o;
    #pragma unroll
    for (int k = 0; k < 4; ++k) {
        float a = fmaxf((tv[k] - mu[k]) * iv[k] + be[k], 0.f);
        o[k] = (_Float16)((float)hv[k] + a);
    }
    *(half4*)(h16 + (size_t)n * 64 + c0) = o;
}

// final BN + mean-pool, run-length aggregated; chunk=16; stats fold inlined
__global__ void k_pool2(const float* __restrict__ h, const float* __restrict__ spart,
                        const float* __restrict__ gamma, const float* __restrict__ beta,
                        const int* __restrict__ batch,
                        float* __restrict__ out, float* __restrict__ cnt) {
    __shared__ float sTmp[256];
    __shared__ float sMS[128];
    {
        int ch = threadIdx.x & 127, hf = threadIdx.x >> 7;
        float a = 0.f;
        #pragma unroll 8
        for (int i = hf; i < SLOTS; i += 2) a += spart[i * 128 + ch];
        sTmp[threadIdx.x] = a;
    }
    __syncthreads();
    if (threadIdx.x < 64) {
        int c = threadIdx.x;
        float s = sTmp[c] + sTmp[128 + c];
        float q = sTmp[64 + c] + sTmp[192 + c];
        float mu = s * (1.f / NN);
        float var = q * (1.f / NN) - mu * mu;
        sMS[c] = mu;
        sMS[64 + c] = rsqrtf(var + EPS_BN);
    }
    __syncthreads();
    int lane = threadIdx.x & 63;
    int w = blockIdx.x * 4 + (threadIdx.x >> 6);
    int n0 = w * 16;
    if (n0 >= NN) return;
    int n1 = min(n0 + 16, NN);
    float mu = sMS[lane];
    float inv = sMS[64 + lane] * gamma[lane];
    float bet = beta[lane];
    float acc = 0.f;
    int run = 0;
    int gcur = batch[n0];
    for (int n = n0; n < n1; ++n) {
        float v = (h[(size_t)n * 64 + lane] - mu) * inv + bet;
        int g = batch[n];
        if (g != gcur) {
            atomicAdd(&out[(size_t)gcur * 64 + lane], acc);
            if (lane == 0) atomicAdd(&cnt[gcur], (float)run);
            acc = 0.f; run = 0; gcur = g;
        }
        acc += v; run++;
    }
    atomicAdd(&out[(size_t)gcur * 64 + lane], acc);
    if (lane == 0) atomicAdd(&cnt[gcur], (float)run);
}

__global__ void k_div(float* __restrict__ out, const float* __restrict__ cnt) {
    int tid = blockIdx.x * blockDim.x + threadIdx.x;
    if (tid >= GH) return;
    out[tid] /= fmaxf(cnt[tid >> 6], 1.0f);
}

extern "C" void kernel_launch(void* const* d_in, const int* in_sizes, int n_in,
                              void* d_out, int out_size, void* d_ws, size_t ws_size,
                              hipStream_t stream) {
    const float* atom_table = (const float*)d_in[0];
    const float* bond_table = (const float*)d_in[1];
    const float* vn0   = (const float*)d_in[2];
    const float* gcn_W = (const float*)d_in[3];
    const float* gcn_b = (const float*)d_in[4];
    const float* ng    = (const float*)d_in[5];
    const float* nb    = (const float*)d_in[6];
    const float* vn_W1 = (const float*)d_in[7];
    const float* vn_b1 = (const float*)d_in[8];
    const float* vn_g1 = (const float*)d_in[9];
    const float* vn_be1= (const float*)d_in[10];
    const float* vn_W2 = (const float*)d_in[11];
    const float* vn_b2 = (const float*)d_in[12];
    const float* vn_g2 = (const float*)d_in[13];
    const float* vn_be2= (const float*)d_in[14];
    const int* x          = (const int*)d_in[15];
    const int* edge_index = (const int*)d_in[16];
    const int* edge_attr  = (const int*)d_in[17];
    const int* batch      = (const int*)d_in[18];

    float* ws = (float*)d_ws;
    float* hB   = ws;                                 // NH fp32 (running h)
    _Float16* h16 = (_Float16*)(ws + (size_t)NH);     // NH fp16 (gather source)
    float* vt   = ws + (size_t)NH + NH / 2;           // GH
    float* t1   = vt + GH;                            // GH
    float* t2   = t1 + GH;                            // GH
    float* convStatsP = t2 + GH;                      // 7 * SLOTS * 128
    float* msAll      = convStatsP + 7 * SLOTS * 128; // 7 * 128 (layout keep)
    float* vn1Stats   = msAll + 7 * 128;              // 6*128
    float* vn2Stats   = vn1Stats + 6 * 128;           // 6*128
    float* cnt    = vn2Stats + 6 * 128;               // GG
    _Float16* ctab16 = (_Float16*)(cnt + GG);         // 60*64 fp16
    _Float16* W16f   = ctab16 + 60 * 64;              // 7*4096 fp16 (fragment order)
    int*   rp     = (int*)(W16f + LL * 4096);         // NN+1 (+1 pad -> even offsets)
    int*   cur    = rp + (NN + 2);                    // NN ints (histogram)
    int*   part   = cur + NN;                         // 128
    unsigned int* edges = (unsigned int*)(part + 128);  // EE
    // recs is CSR-build scratch only; alias the h16 region (atom_enc runs after fill2)
    unsigned int* recs = (unsigned int*)h16;            // EE (4MB <= 12.8MB h16)

    const int blkN = NH / 256;               // 25000
    const int blkG = (GH + 255) / 256;       // 128
    const int blkE = (EE + 255) / 256;       // 3907
    const int blkRL = ((NN + 7) / 8 + 3) / 4;   // 3125
    const int blkPL = ((NN + 15) / 16 + 3) / 4; // 1563
    const int blkAV = (NN * 16) / 256;       // 6250
    const int blkPR = (LL * 4096 + 60 * 64 + 255) / 256;  // 127
    float* outp = (float*)d_out;

    // ---- CSR build first (recs aliases h16; must finish before k_atom_enc) ----
    hipMemsetAsync(cur, 0, (size_t)NN * 4, stream);
    k_count2<<<blkE, 256, 0, stream>>>(edge_index, edge_attr, cur, recs);
    k_scan1<<<SCAN_BLKS, 256, 0, stream>>>(cur, rp, part);
    k_scan3<<<(NN + 255) / 256, 256, 0, stream>>>(rp, part);   // scan2 folded in
    k_fill2<<<blkE, 256, 0, stream>>>(edge_index, recs, rp, edges);

    k_atom_enc<<<blkN, 256, 0, stream>>>(atom_table, vn0, x, h16);
    k_prep<<<blkPR, 256, 0, stream>>>(gcn_W, bond_table, W16f, ctab16);
    hipMemsetAsync(convStatsP, 0, (7 * SLOTS * 128 + 7 * 128 + 12 * 128) * 4, stream);
    hipMemsetAsync(vt, 0, (size_t)GH * 4, stream);

    // ---- layer 0: hB = (h16 + agg(h16)) @ W0 + b0 ----
    k_conv_mfma<<<CONV_BLOCKS, 128, 0, stream>>>(h16, nullptr, rp, edges, ctab16, W16f,
                                                 gcn_b, hB, convStatsP);

    for (int l = 1; l < LL; ++l) {
        // h16 = relu(bn(hB)) (stats folded in-block); vt = segment_sum(h16)
        k_bn_relu_vt2<<<blkRL, 256, 0, stream>>>(hB, convStatsP + (size_t)(l - 1) * SLOTS * 128,
                                                 ng + (size_t)(l - 1) * HH,
                                                 nb + (size_t)(l - 1) * HH, batch, h16, vt);
        // t1 = (vt + vn_prev) @ W1 + b1 ; vn_prev = l==1 ? vn0 : bnrelu(t2, vn2Stats[l-2])
        if (l == 1)
            k_vn_gemm<<<32, 256, 0, stream>>>(vt, 1, nullptr, nullptr, nullptr,
                                              nullptr, nullptr, nullptr, nullptr, vn0,
                                              vn_W1, vn_b1, t1, vn1Stats);
        else
            k_vn_gemm<<<32, 256, 0, stream>>>(vt, 1, nullptr, nullptr, nullptr,
                                              t2, vn2Stats + (size_t)(l - 2) * 128,
                                              vn_g2 + (size_t)(l - 2) * HH,
                                              vn_be2 + (size_t)(l - 2) * HH, nullptr,
                                              vn_W1 + (size_t)(l - 1) * 4096,
                                              vn_b1 + (size_t)(l - 1) * HH, t1,
                                              vn1Stats + (size_t)(l - 1) * 128);
        // t2 = bnrelu(t1) @ W2 + b2
        k_vn_gemm<<<32, 256, 0, stream>>>(t1, 0, vn1Stats + (size_t)(l - 1) * 128,
                                          vn_g1 + (size_t)(l - 1) * HH,
                                          vn_be1 + (size_t)(l - 1) * HH,
                                          nullptr, nullptr, nullptr, nullptr, nullptr,
                                          vn_W2 + (size_t)(l - 1) * 4096,
                                          vn_b2 + (size_t)(l - 1) * HH, t2,
                                          vn2Stats + (size_t)(l - 1) * 128);
        // h16 += bnrelu(t2)[batch]
        k_addvn16<<<blkAV, 256, 0, stream>>>(h16, t2, vn2Stats + (size_t)(l - 1) * 128,
                                             vn_g2 + (size_t)(l - 1) * HH,
                                             vn_be2 + (size_t)(l - 1) * HH, batch);

        k_conv_mfma<<<CONV_BLOCKS, 128, 0, stream>>>(h16, hB, rp, edges, ctab16,
                                                     W16f + (size_t)l * 4096,
                                                     gcn_b + (size_t)l * HH, hB,
                                                     convStatsP + (size_t)l * SLOTS * 128);
    }

    // ---- final BN + mean pool (stats fold inlined in k_pool2) ----
    hipMemsetAsync(outp, 0, (size_t)GH * 4, stream);
    hipMemsetAsync(cnt, 0, (size_t)GG * 4, stream);
    k_pool2<<<blkPL, 256, 0, stream>>>(hB, convStatsP + (size_t)6 * SLOTS * 128,
                                       ng + (size_t)6 * HH, nb + (size_t)6 * HH,
                                       batch, outp, cnt);
    k_div<<<blkG, 256, 0, stream>>>(outp, cnt);
}